// Round 7
// baseline (319.484 us; speedup 1.0000x reference)
//
#include <hip/hip_runtime.h>
#include <hip/hip_fp16.h>

#define NN 100000
#define NE 6400000
#define NEG_SLOPE 0.2f

// ---- binned path geometry ----
#define SLICE 200              // nodes per bin (sacc = 200*3 floats = 2.4 KB)
#define NSLICE 500             // 500 * 200 = 100000 = NN exactly
#define ABLK 256               // hist/scatter blocks
#define EPB (NE / ABLK)        // 25000 edges per block, %4 == 0

// ---- fallback (r5) geometry ----
#define FSLICE 10240
#define FNSLICE 10
#define FNCHUNK 20
#define FCHUNK (NE / FNCHUNK)

// ---------------- node pass: pack={h0,h1,a_src,a_dst}, scalar tables -------
__global__ void gat_node(const float* __restrict__ x, const float* __restrict__ W,
                         const float* __restrict__ att_src, const float* __restrict__ att_dst,
                         float4* __restrict__ pack, float* __restrict__ asrc,
                         float* __restrict__ adst, int n) {
    int gtid = blockIdx.x * blockDim.x + threadIdx.x;
    int wave = gtid >> 6, lane = threadIdx.x & 63;
    int nw = (gridDim.x * blockDim.x) >> 6;
    float as0 = att_src[0], as1 = att_src[1];
    float ad0 = att_dst[0], ad1 = att_dst[1];
    for (int node = wave; node < n; node += nw) {
        float2 xx = *(const float2*)(x + (size_t)node * 128 + lane * 2);
        float2 w0 = *(const float2*)(W + lane * 4);
        float2 w1 = *(const float2*)(W + lane * 4 + 2);
        float c0 = xx.x * w0.x + xx.y * w1.x;
        float c1 = xx.x * w0.y + xx.y * w1.y;
        #pragma unroll
        for (int off = 32; off; off >>= 1) {
            c0 += __shfl_down(c0, off);
            c1 += __shfl_down(c1, off);
        }
        if (lane == 0) {
            float s = c0 * as0 + c1 * as1;
            float d = c0 * ad0 + c1 * ad1;
            pack[node] = make_float4(c0, c1, s, d);
            asrc[node] = s;
            adst[node] = d;
        }
    }
}

// ---------------- phase A1: per-(block,bin) histogram ----------------------
__global__ __launch_bounds__(1024) void
gat_hist(const int* __restrict__ dst, int* __restrict__ cnt) {
    __shared__ unsigned h[NSLICE];
    const int ablk = blockIdx.x, t = threadIdx.x;
    if (t < NSLICE) h[t] = 0;
    __syncthreads();
    const int b0 = ablk * EPB;
    for (int o = t * 4; o < EPB; o += 4096) {
        int4 d4 = *(const int4*)(dst + b0 + o);
        const int* dp = (const int*)&d4;
        #pragma unroll
        for (int u = 0; u < 4; ++u)
            atomicAdd(&h[(unsigned)dp[u] / SLICE], 1u);
    }
    __syncthreads();
    if (t < NSLICE) cnt[ablk * NSLICE + t] = (int)h[t];
}

// ---------------- phase A2: parallel prefix -> per-(block,bin) bases -------
__global__ __launch_bounds__(512) void
gat_prefix(int* __restrict__ cnt, int* __restrict__ binstart) {
    __shared__ int sc[512];
    const int t = threadIdx.x;
    int sum = 0;
    if (t < NSLICE)
        for (int a = 0; a < ABLK; ++a) sum += cnt[a * NSLICE + t];
    sc[t] = (t < NSLICE) ? sum : 0;
    __syncthreads();
    #pragma unroll
    for (int d = 1; d < 512; d <<= 1) {          // Hillis-Steele inclusive scan
        int v = (t >= d) ? sc[t - d] : 0;
        __syncthreads();
        sc[t] += v;
        __syncthreads();
    }
    if (t < NSLICE) {
        int run = sc[t] - sum;                   // exclusive
        binstart[t] = run;
        for (int a = 0; a < ABLK; ++a) {
            int c = cnt[a * NSLICE + t];
            cnt[a * NSLICE + t] = run;
            run += c;
        }
        if (t == NSLICE - 1) binstart[NSLICE] = sc[t];
    }
}

// ---------------- phase A3: scatter SELF-CONTAINED 8B records --------------
// rec = { f16(h0) | f16(h1)<<16 ,  f16(lrelu_logit) | off<<16 }
// All per-edge math done HERE (262K threads of TLP hide the gathers);
// the scan consumer becomes a pure stream with zero gathers.
__global__ __launch_bounds__(1024) void
gat_scatter(const int* __restrict__ src, const int* __restrict__ dst,
            const float* __restrict__ ea, const float4* __restrict__ pack,
            const float* __restrict__ adst,
            const float* __restrict__ W_edge, const float* __restrict__ att_edge,
            const int* __restrict__ base, uint2* __restrict__ recs) {
    __shared__ unsigned cursor[NSLICE];
    const int ablk = blockIdx.x, t = threadIdx.x;
    if (t < NSLICE) cursor[t] = (unsigned)base[ablk * NSLICE + t];
    __syncthreads();
    const float k = W_edge[0] * att_edge[0] + W_edge[1] * att_edge[1];
    const int b0 = ablk * EPB;
    for (int o = t * 4; o < EPB; o += 4096) {
        const int i = b0 + o;
        int4 s4 = *(const int4*)(src + i);
        int4 d4 = *(const int4*)(dst + i);
        float4 e4 = *(const float4*)(ea + i);
        const int* sp = (const int*)&s4;
        const int* dp = (const int*)&d4;
        const float* ep = (const float*)&e4;
        float4 ps[4];
        float  ad[4];
        #pragma unroll
        for (int u = 0; u < 4; ++u) {            // load-only stage
            ps[u] = pack[sp[u]];
            ad[u] = adst[dp[u]];
        }
        #pragma unroll
        for (int u = 0; u < 4; ++u) {
            unsigned d = (unsigned)dp[u];
            unsigned bin = d / SLICE;
            unsigned off = d - bin * SLICE;
            float al = ps[u].z + ad[u] + k * ep[u];
            al = al > 0.0f ? al : NEG_SLOPE * al;
            unsigned pos = atomicAdd(&cursor[bin], 1u);
            unsigned hh = (unsigned)__half_as_ushort(__float2half_rn(ps[u].x)) |
                          ((unsigned)__half_as_ushort(__float2half_rn(ps[u].y)) << 16);
            unsigned lo = (unsigned)__half_as_ushort(__float2half_rn(al)) | (off << 16);
            recs[pos] = make_uint2(hh, lo);
        }
    }
}

// ---------------- phase B: pure-stream scan, direct final output -----------
__global__ __launch_bounds__(1024) void
gat_scan(const uint2* __restrict__ recs, const int* __restrict__ binstart,
         const float* __restrict__ bias,
         float* __restrict__ out, float* __restrict__ invd) {
    __shared__ float sacc[SLICE * 3];
    const int s = blockIdx.x, t = threadIdx.x;
    for (int j = t; j < SLICE * 3; j += 1024) sacc[j] = 0.f;
    __syncthreads();
    const int start = binstart[s], end = binstart[s + 1];

#define PROC(r)                                                                \
    do {                                                                       \
        unsigned off_ = (r).y >> 16;                                           \
        float al_ = __half2float(__ushort_as_half((unsigned short)((r).y & 0xFFFFu))); \
        float ex_ = __expf(al_);                                               \
        float h0_ = __half2float(__ushort_as_half((unsigned short)((r).x & 0xFFFFu))); \
        float h1_ = __half2float(__ushort_as_half((unsigned short)((r).x >> 16)));     \
        atomicAdd(&sacc[off_ * 3],     ex_);                                   \
        atomicAdd(&sacc[off_ * 3 + 1], ex_ * h0_);                             \
        atomicAdd(&sacc[off_ * 3 + 2], ex_ * h1_);                             \
    } while (0)

    int i = start + t;
    for (; i + 1024 < end; i += 2048) {          // 2 independent loads/iter
        uint2 ra = recs[i], rb = recs[i + 1024];
        PROC(ra);
        PROC(rb);
    }
    if (i < end) {
        uint2 r = recs[i];
        PROC(r);
    }
#undef PROC
    __syncthreads();
    if (t < SLICE) {
        float de = sacc[t * 3], n0 = sacc[t * 3 + 1], n1 = sacc[t * 3 + 2];
        float inv = 1.0f / (de + 1e-16f);
        int node = s * SLICE + t;
        *(float2*)(out + 2 * node) = make_float2(n0 * inv + bias[0], n1 * inv + bias[1]);
        invd[node] = inv;
    }
}

// ---------------- alpha pass: recompute ex in f32, alpha = ex*invd[dst] ----
__global__ void gat_alpha(const int* __restrict__ src, const int* __restrict__ dst,
                          const float* __restrict__ ea,
                          const float* __restrict__ asrc, const float* __restrict__ adst,
                          const float* __restrict__ W_edge, const float* __restrict__ att_edge,
                          const float* __restrict__ invd, float* __restrict__ alpha) {
    const float k = W_edge[0] * att_edge[0] + W_edge[1] * att_edge[1];
    int i = (blockIdx.x * blockDim.x + threadIdx.x) * 4;
    if (i >= NE) return;
    int4   d4 = *(const int4*)(dst + i);
    int4   s4 = *(const int4*)(src + i);
    float4 e4 = *(const float4*)(ea + i);
    const int*   dp = (const int*)&d4;
    const int*   sp = (const int*)&s4;
    const float* ep = (const float*)&e4;
    float as[4], ad[4], iv[4];
    #pragma unroll
    for (int u = 0; u < 4; ++u) {
        as[u] = asrc[sp[u]];
        ad[u] = adst[dp[u]];
        iv[u] = invd[dp[u]];
    }
    float4 a;
    float* ap = (float*)&a;
    #pragma unroll
    for (int u = 0; u < 4; ++u) {
        float al = as[u] + ad[u] + k * ep[u];
        al = al > 0.0f ? al : NEG_SLOPE * al;
        ap[u] = __expf(al) * iv[u];
    }
    *(float4*)(alpha + i) = a;
}

// ================== fallback (r5) kernels — used only if ws is small =======
__global__ __launch_bounds__(1024) void
gat_scan_fb(const int* __restrict__ src, const int* __restrict__ dst,
            const float* __restrict__ ea, const float4* __restrict__ pack,
            const float* __restrict__ adst,
            const float* __restrict__ W_edge, const float* __restrict__ att_edge,
            float* __restrict__ partial) {
    __shared__ float sacc[FSLICE * 3];
    const int s = blockIdx.x / FNCHUNK;
    const int c = blockIdx.x % FNCHUNK;
    const int lo = s * FSLICE;
    for (int j = threadIdx.x; j < FSLICE * 3; j += 1024) sacc[j] = 0.0f;
    __syncthreads();
    const float k = W_edge[0] * att_edge[0] + W_edge[1] * att_edge[1];
    const int base = c * FCHUNK;
    for (int o = threadIdx.x * 8; o < FCHUNK; o += 1024 * 8) {
        const int i = base + o;
        int4   da = *(const int4*)(dst + i), db = *(const int4*)(dst + i + 4);
        int4   sa = *(const int4*)(src + i), sb = *(const int4*)(src + i + 4);
        float4 e0 = *(const float4*)(ea + i), e1 = *(const float4*)(ea + i + 4);
        int   dd[8] = {da.x, da.y, da.z, da.w, db.x, db.y, db.z, db.w};
        int   ss[8] = {sa.x, sa.y, sa.z, sa.w, sb.x, sb.y, sb.z, sb.w};
        float ee[8] = {e0.x, e0.y, e0.z, e0.w, e1.x, e1.y, e1.z, e1.w};
        unsigned off[8];
        float4 ps[8];
        float  ad[8];
        #pragma unroll
        for (int u = 0; u < 8; ++u) {
            off[u] = (unsigned)(dd[u] - lo);
            bool acc = off[u] < FSLICE;
            ps[u] = pack[acc ? ss[u] : 0];
            ad[u] = adst[acc ? dd[u] : lo];
        }
        #pragma unroll
        for (int u = 0; u < 8; ++u) {
            float al = ps[u].z + ad[u] + k * ee[u];
            al = al > 0.0f ? al : NEG_SLOPE * al;
            float ex = __expf(al);
            if (off[u] < FSLICE) {
                atomicAdd(&sacc[off[u] * 3],     ex);
                atomicAdd(&sacc[off[u] * 3 + 1], ex * ps[u].x);
                atomicAdd(&sacc[off[u] * 3 + 2], ex * ps[u].y);
            }
        }
    }
    __syncthreads();
    float* pout = partial + (size_t)blockIdx.x * (FSLICE * 3);
    for (int j = threadIdx.x; j < FSLICE * 3; j += 1024) pout[j] = sacc[j];
}

__global__ void gat_combine_fb(const float* __restrict__ partial,
                               const float* __restrict__ bias,
                               float* __restrict__ out, float* __restrict__ invd) {
    int n = blockIdx.x * blockDim.x + threadIdx.x;
    if (n >= NN) return;
    int sl = n / FSLICE, off = n % FSLICE;
    const float* p = partial + (size_t)sl * FNCHUNK * (FSLICE * 3) + (size_t)off * 3;
    float de = 0.f, n0 = 0.f, n1 = 0.f;
    for (int c = 0; c < FNCHUNK; ++c, p += FSLICE * 3) {
        de += p[0]; n0 += p[1]; n1 += p[2];
    }
    float inv = 1.0f / (de + 1e-16f);
    out[2 * n]     = n0 * inv + bias[0];
    out[2 * n + 1] = n1 * inv + bias[1];
    invd[n] = inv;
}

extern "C" void kernel_launch(void* const* d_in, const int* in_sizes, int n_in,
                              void* d_out, int out_size, void* d_ws, size_t ws_size,
                              hipStream_t stream) {
    const float* x        = (const float*)d_in[0];
    const int*   ei       = (const int*)  d_in[1];
    const float* ea       = (const float*)d_in[2];
    const float* W_src    = (const float*)d_in[3];
    const float* W_edge   = (const float*)d_in[4];
    const float* att_src  = (const float*)d_in[5];
    const float* att_dst  = (const float*)d_in[6];
    const float* att_edge = (const float*)d_in[7];
    const float* bias     = (const float*)d_in[8];

    float* out   = (float*)d_out;      // [N,2]
    float* alpha = out + 2 * NN;       // [E]

    const int* src = ei;
    const int* dst = ei + NE;

    size_t need = (size_t)NE * 8 + (size_t)NN * 16 + 3 * (size_t)NN * 4
                + (size_t)ABLK * NSLICE * 4 + (NSLICE + 1) * 4 + 64;

    if (ws_size >= need) {
        uint2*  recs = (uint2*)d_ws;
        float4* pack = (float4*)((char*)d_ws + (size_t)NE * 8);
        float*  asrc = (float*)(pack + NN);
        float*  adst = asrc + NN;
        float*  invd = adst + NN;
        int*    cnt  = (int*)(invd + NN);
        int*    binstart = cnt + ABLK * NSLICE;

        gat_node   <<<1024, 256, 0, stream>>>(x, W_src, att_src, att_dst, pack, asrc, adst, NN);
        gat_hist   <<<ABLK, 1024, 0, stream>>>(dst, cnt);
        gat_prefix <<<1, 512, 0, stream>>>(cnt, binstart);
        gat_scatter<<<ABLK, 1024, 0, stream>>>(src, dst, ea, pack, adst,
                                               W_edge, att_edge, cnt, recs);
        gat_scan   <<<NSLICE, 1024, 0, stream>>>(recs, binstart, bias, out, invd);
        gat_alpha  <<<NE / (256 * 4), 256, 0, stream>>>(src, dst, ea, asrc, adst,
                                                        W_edge, att_edge, invd, alpha);
    } else {
        float4* pack = (float4*)d_ws;
        float*  asrc = (float*)(pack + NN);
        float*  adst = asrc + NN;
        float*  invd = adst + NN;
        float*  partial = alpha;

        gat_node      <<<1024, 256, 0, stream>>>(x, W_src, att_src, att_dst, pack, asrc, adst, NN);
        gat_scan_fb   <<<FNSLICE * FNCHUNK, 1024, 0, stream>>>(src, dst, ea, pack, adst,
                                                               W_edge, att_edge, partial);
        gat_combine_fb<<<(NN + 255) / 256, 256, 0, stream>>>(partial, bias, out, invd);
        gat_alpha     <<<NE / (256 * 4), 256, 0, stream>>>(src, dst, ea, asrc, adst,
                                                           W_edge, att_edge, invd, alpha);
    }
}

// Round 8
// 278.655 us; speedup vs baseline: 1.1465x; 1.1465x over previous
//
#include <hip/hip_runtime.h>
#include <hip/hip_fp16.h>

#define NN 100000
#define NE 6400000
#define NEG_SLOPE 0.2f

// ---- binned path geometry ----
#define NBIN 16                // coarse dst-bins
#define BSLICE 6250            // nodes per bin (16*6250 = 100000 exactly)
#define NCH 16                 // scan chunks per bin -> 256 scan blocks
#define SACC (BSLICE * 3)      // 18750 floats = 75000 B LDS
#define ABLK 256               // hist/scatter blocks
#define EPB (NE / ABLK)        // 25000 edges per block, %4 == 0

// ---- fallback (r5) geometry ----
#define FSLICE 10240
#define FNSLICE 10
#define FNCHUNK 20
#define FCHUNK (NE / FNCHUNK)

// ---------------- node pass: pack={h0,h1,a_src,a_dst}, scalar tables -------
__global__ void gat_node(const float* __restrict__ x, const float* __restrict__ W,
                         const float* __restrict__ att_src, const float* __restrict__ att_dst,
                         float4* __restrict__ pack, float* __restrict__ asrc,
                         float* __restrict__ adst, int n) {
    int gtid = blockIdx.x * blockDim.x + threadIdx.x;
    int wave = gtid >> 6, lane = threadIdx.x & 63;
    int nw = (gridDim.x * blockDim.x) >> 6;
    float as0 = att_src[0], as1 = att_src[1];
    float ad0 = att_dst[0], ad1 = att_dst[1];
    for (int node = wave; node < n; node += nw) {
        float2 xx = *(const float2*)(x + (size_t)node * 128 + lane * 2);
        float2 w0 = *(const float2*)(W + lane * 4);
        float2 w1 = *(const float2*)(W + lane * 4 + 2);
        float c0 = xx.x * w0.x + xx.y * w1.x;
        float c1 = xx.x * w0.y + xx.y * w1.y;
        #pragma unroll
        for (int off = 32; off; off >>= 1) {
            c0 += __shfl_down(c0, off);
            c1 += __shfl_down(c1, off);
        }
        if (lane == 0) {
            float s = c0 * as0 + c1 * as1;
            float d = c0 * ad0 + c1 * ad1;
            pack[node] = make_float4(c0, c1, s, d);
            asrc[node] = s;
            adst[node] = d;
        }
    }
}

// ---------------- phase A1: per-(block,bin) histogram ----------------------
__global__ __launch_bounds__(1024) void
gat_hist(const int* __restrict__ dst, int* __restrict__ cnt) {
    __shared__ unsigned h[NBIN];
    const int ablk = blockIdx.x, t = threadIdx.x;
    if (t < NBIN) h[t] = 0;
    __syncthreads();
    const int b0 = ablk * EPB;
    for (int o = t * 4; o < EPB; o += 4096) {
        int4 d4 = *(const int4*)(dst + b0 + o);
        const int* dp = (const int*)&d4;
        #pragma unroll
        for (int u = 0; u < 4; ++u)
            atomicAdd(&h[(unsigned)dp[u] / BSLICE], 1u);
    }
    __syncthreads();
    if (t < NBIN) cnt[t * ABLK + ablk] = (int)h[t];
}

// ---------------- phase A2: 16-wave shfl prefix -> per-(bin,block) bases ---
__global__ __launch_bounds__(1024) void
gat_prefix(int* __restrict__ cnt, int* __restrict__ binstart) {
    __shared__ int btot[NBIN];
    __shared__ int bst[NBIN + 1];
    const int t = threadIdx.x, w = t >> 6, l = t & 63;   // wave w owns bin w
    int c0 = cnt[w * ABLK + l * 4];
    int c1 = cnt[w * ABLK + l * 4 + 1];
    int c2 = cnt[w * ABLK + l * 4 + 2];
    int c3 = cnt[w * ABLK + l * 4 + 3];
    int s = c0 + c1 + c2 + c3;
    int incl = s;
    #pragma unroll
    for (int d = 1; d < 64; d <<= 1) {
        int v = __shfl_up(incl, d);
        if (l >= d) incl += v;
    }
    if (l == 63) btot[w] = incl;
    __syncthreads();
    if (t == 0) {
        int run = 0;
        for (int b = 0; b < NBIN; ++b) { bst[b] = run; run += btot[b]; }
        bst[NBIN] = run;
    }
    __syncthreads();
    int base = bst[w] + incl - s;                       // exclusive within bin
    cnt[w * ABLK + l * 4]     = base;
    cnt[w * ABLK + l * 4 + 1] = base + c0;
    cnt[w * ABLK + l * 4 + 2] = base + c0 + c1;
    cnt[w * ABLK + l * 4 + 3] = base + c0 + c1 + c2;
    if (t <= NBIN) binstart[t] = bst[t];
}

// ---------------- phase A3: scatter self-contained 8B records --------------
// rec = { f16(h0)|f16(h1)<<16 , f16(lrelu_logit)|off<<16 }.  With only 16
// bins, the LDS cursor atomicAdd hands a wave's same-bin lanes CONSECUTIVE
// positions -> each store instruction writes ~16 runs of ~32B -> L2 merges
// into full lines (16 streams/block instead of 500).
__global__ __launch_bounds__(1024) void
gat_scatter(const int* __restrict__ src, const int* __restrict__ dst,
            const float* __restrict__ ea, const float4* __restrict__ pack,
            const float* __restrict__ adst,
            const float* __restrict__ W_edge, const float* __restrict__ att_edge,
            const int* __restrict__ base, uint2* __restrict__ recs) {
    __shared__ unsigned cursor[NBIN];
    const int ablk = blockIdx.x, t = threadIdx.x;
    if (t < NBIN) cursor[t] = (unsigned)base[t * ABLK + ablk];
    __syncthreads();
    const float k = W_edge[0] * att_edge[0] + W_edge[1] * att_edge[1];
    const int b0 = ablk * EPB;
    for (int o = t * 4; o < EPB; o += 4096) {
        const int i = b0 + o;
        int4 s4 = *(const int4*)(src + i);
        int4 d4 = *(const int4*)(dst + i);
        float4 e4 = *(const float4*)(ea + i);
        const int* sp = (const int*)&s4;
        const int* dp = (const int*)&d4;
        const float* ep = (const float*)&e4;
        float4 ps[4];
        float  ad[4];
        #pragma unroll
        for (int u = 0; u < 4; ++u) {            // load-only stage
            ps[u] = pack[sp[u]];
            ad[u] = adst[dp[u]];
        }
        #pragma unroll
        for (int u = 0; u < 4; ++u) {
            unsigned d = (unsigned)dp[u];
            unsigned bin = d / BSLICE;
            unsigned off = d - bin * BSLICE;     // < 6250, fits 13 bits
            float al = ps[u].z + ad[u] + k * ep[u];
            al = al > 0.0f ? al : NEG_SLOPE * al;
            unsigned pos = atomicAdd(&cursor[bin], 1u);
            unsigned hh = (unsigned)__half_as_ushort(__float2half_rn(ps[u].x)) |
                          ((unsigned)__half_as_ushort(__float2half_rn(ps[u].y)) << 16);
            unsigned lo = (unsigned)__half_as_ushort(__float2half_rn(al)) | (off << 16);
            recs[pos] = make_uint2(hh, lo);
        }
    }
}

// ---------------- phase B: pure-stream scan over bin chunk, partial dump ---
__global__ __launch_bounds__(1024) void
gat_scan(const uint2* __restrict__ recs, const int* __restrict__ binstart,
         float* __restrict__ partial) {
    __shared__ float sacc[SACC];                 // 75000 B -> 2 blocks/CU
    const int blk = blockIdx.x, t = threadIdx.x;
    const int b = blk / NCH, c = blk % NCH;
    for (int j = t; j < SACC; j += 1024) sacc[j] = 0.f;
    __syncthreads();
    const int s0 = binstart[b], len = binstart[b + 1] - s0;
    const int c0 = s0 + (int)((long long)len * c / NCH);
    const int c1 = s0 + (int)((long long)len * (c + 1) / NCH);

#define PROC(r)                                                                \
    do {                                                                       \
        unsigned off_ = (r).y >> 16;                                           \
        float al_ = __half2float(__ushort_as_half((unsigned short)((r).y & 0xFFFFu))); \
        float ex_ = __expf(al_);                                               \
        float h0_ = __half2float(__ushort_as_half((unsigned short)((r).x & 0xFFFFu))); \
        float h1_ = __half2float(__ushort_as_half((unsigned short)((r).x >> 16)));     \
        atomicAdd(&sacc[off_ * 3],     ex_);                                   \
        atomicAdd(&sacc[off_ * 3 + 1], ex_ * h0_);                             \
        atomicAdd(&sacc[off_ * 3 + 2], ex_ * h1_);                             \
    } while (0)

    int i = c0 + t;
    for (; i + 3072 < c1; i += 4096) {           // 4 independent loads/iter
        uint2 r0 = recs[i], r1 = recs[i + 1024], r2 = recs[i + 2048], r3 = recs[i + 3072];
        PROC(r0); PROC(r1); PROC(r2); PROC(r3);
    }
    for (; i < c1; i += 1024) {
        uint2 r = recs[i];
        PROC(r);
    }
#undef PROC
    __syncthreads();
    float* p = partial + (size_t)blk * SACC;
    for (int j = t; j < SACC; j += 1024) p[j] = sacc[j];
}

// ---------------- combine 16 partials: out = num/denom + bias, invd --------
__global__ void gat_combine(const float* __restrict__ partial,
                            const float* __restrict__ bias,
                            float* __restrict__ out, float* __restrict__ invd) {
    int n = blockIdx.x * blockDim.x + threadIdx.x;
    if (n >= NN) return;
    int b = n / BSLICE, off = n % BSLICE;
    const float* p = partial + (size_t)(b * NCH) * SACC + (size_t)off * 3;
    float de = 0.f, n0 = 0.f, n1 = 0.f;
    for (int c = 0; c < NCH; ++c, p += SACC) {
        de += p[0]; n0 += p[1]; n1 += p[2];
    }
    float inv = 1.0f / (de + 1e-16f);
    out[2 * n]     = n0 * inv + bias[0];
    out[2 * n + 1] = n1 * inv + bias[1];
    invd[n] = inv;
}

// ---------------- alpha pass: recompute ex in f32, alpha = ex*invd[dst] ----
__global__ void gat_alpha(const int* __restrict__ src, const int* __restrict__ dst,
                          const float* __restrict__ ea,
                          const float* __restrict__ asrc, const float* __restrict__ adst,
                          const float* __restrict__ W_edge, const float* __restrict__ att_edge,
                          const float* __restrict__ invd, float* __restrict__ alpha) {
    const float k = W_edge[0] * att_edge[0] + W_edge[1] * att_edge[1];
    int i = (blockIdx.x * blockDim.x + threadIdx.x) * 4;
    if (i >= NE) return;
    int4   d4 = *(const int4*)(dst + i);
    int4   s4 = *(const int4*)(src + i);
    float4 e4 = *(const float4*)(ea + i);
    const int*   dp = (const int*)&d4;
    const int*   sp = (const int*)&s4;
    const float* ep = (const float*)&e4;
    float as[4], ad[4], iv[4];
    #pragma unroll
    for (int u = 0; u < 4; ++u) {
        as[u] = asrc[sp[u]];
        ad[u] = adst[dp[u]];
        iv[u] = invd[dp[u]];
    }
    float4 a;
    float* ap = (float*)&a;
    #pragma unroll
    for (int u = 0; u < 4; ++u) {
        float al = as[u] + ad[u] + k * ep[u];
        al = al > 0.0f ? al : NEG_SLOPE * al;
        ap[u] = __expf(al) * iv[u];
    }
    *(float4*)(alpha + i) = a;
}

// ================== fallback (r5) kernels — used only if ws is small =======
__global__ __launch_bounds__(1024) void
gat_scan_fb(const int* __restrict__ src, const int* __restrict__ dst,
            const float* __restrict__ ea, const float4* __restrict__ pack,
            const float* __restrict__ adst,
            const float* __restrict__ W_edge, const float* __restrict__ att_edge,
            float* __restrict__ partial) {
    __shared__ float sacc[FSLICE * 3];
    const int s = blockIdx.x / FNCHUNK;
    const int c = blockIdx.x % FNCHUNK;
    const int lo = s * FSLICE;
    for (int j = threadIdx.x; j < FSLICE * 3; j += 1024) sacc[j] = 0.0f;
    __syncthreads();
    const float k = W_edge[0] * att_edge[0] + W_edge[1] * att_edge[1];
    const int base = c * FCHUNK;
    for (int o = threadIdx.x * 8; o < FCHUNK; o += 1024 * 8) {
        const int i = base + o;
        int4   da = *(const int4*)(dst + i), db = *(const int4*)(dst + i + 4);
        int4   sa = *(const int4*)(src + i), sb = *(const int4*)(src + i + 4);
        float4 e0 = *(const float4*)(ea + i), e1 = *(const float4*)(ea + i + 4);
        int   dd[8] = {da.x, da.y, da.z, da.w, db.x, db.y, db.z, db.w};
        int   ss[8] = {sa.x, sa.y, sa.z, sa.w, sb.x, sb.y, sb.z, sb.w};
        float ee[8] = {e0.x, e0.y, e0.z, e0.w, e1.x, e1.y, e1.z, e1.w};
        unsigned off[8];
        float4 ps[8];
        float  ad[8];
        #pragma unroll
        for (int u = 0; u < 8; ++u) {
            off[u] = (unsigned)(dd[u] - lo);
            bool acc = off[u] < FSLICE;
            ps[u] = pack[acc ? ss[u] : 0];
            ad[u] = adst[acc ? dd[u] : lo];
        }
        #pragma unroll
        for (int u = 0; u < 8; ++u) {
            float al = ps[u].z + ad[u] + k * ee[u];
            al = al > 0.0f ? al : NEG_SLOPE * al;
            float ex = __expf(al);
            if (off[u] < FSLICE) {
                atomicAdd(&sacc[off[u] * 3],     ex);
                atomicAdd(&sacc[off[u] * 3 + 1], ex * ps[u].x);
                atomicAdd(&sacc[off[u] * 3 + 2], ex * ps[u].y);
            }
        }
    }
    __syncthreads();
    float* pout = partial + (size_t)blockIdx.x * (FSLICE * 3);
    for (int j = threadIdx.x; j < FSLICE * 3; j += 1024) pout[j] = sacc[j];
}

__global__ void gat_combine_fb(const float* __restrict__ partial,
                               const float* __restrict__ bias,
                               float* __restrict__ out, float* __restrict__ invd) {
    int n = blockIdx.x * blockDim.x + threadIdx.x;
    if (n >= NN) return;
    int sl = n / FSLICE, off = n % FSLICE;
    const float* p = partial + (size_t)sl * FNCHUNK * (FSLICE * 3) + (size_t)off * 3;
    float de = 0.f, n0 = 0.f, n1 = 0.f;
    for (int c = 0; c < FNCHUNK; ++c, p += FSLICE * 3) {
        de += p[0]; n0 += p[1]; n1 += p[2];
    }
    float inv = 1.0f / (de + 1e-16f);
    out[2 * n]     = n0 * inv + bias[0];
    out[2 * n + 1] = n1 * inv + bias[1];
    invd[n] = inv;
}

extern "C" void kernel_launch(void* const* d_in, const int* in_sizes, int n_in,
                              void* d_out, int out_size, void* d_ws, size_t ws_size,
                              hipStream_t stream) {
    const float* x        = (const float*)d_in[0];
    const int*   ei       = (const int*)  d_in[1];
    const float* ea       = (const float*)d_in[2];
    const float* W_src    = (const float*)d_in[3];
    const float* W_edge   = (const float*)d_in[4];
    const float* att_src  = (const float*)d_in[5];
    const float* att_dst  = (const float*)d_in[6];
    const float* att_edge = (const float*)d_in[7];
    const float* bias     = (const float*)d_in[8];

    float* out   = (float*)d_out;      // [N,2]
    float* alpha = out + 2 * NN;       // [E]: partial slabs first, then alpha

    const int* src = ei;
    const int* dst = ei + NE;

    size_t need = (size_t)NE * 8 + (size_t)NN * 16 + 3 * (size_t)NN * 4
                + (size_t)NBIN * ABLK * 4 + (NBIN + 1) * 4 + 64;

    if (ws_size >= need) {
        uint2*  recs = (uint2*)d_ws;
        float4* pack = (float4*)((char*)d_ws + (size_t)NE * 8);
        float*  asrc = (float*)(pack + NN);
        float*  adst = asrc + NN;
        float*  invd = adst + NN;
        int*    cnt  = (int*)(invd + NN);
        int*    binstart = cnt + NBIN * ABLK;
        // partial slabs: 256 * 18750 floats = 19.2 MB <= 25.6 MB alpha region
        float*  partial = alpha;

        gat_node   <<<1024, 256, 0, stream>>>(x, W_src, att_src, att_dst, pack, asrc, adst, NN);
        gat_hist   <<<ABLK, 1024, 0, stream>>>(dst, cnt);
        gat_prefix <<<1, 1024, 0, stream>>>(cnt, binstart);
        gat_scatter<<<ABLK, 1024, 0, stream>>>(src, dst, ea, pack, adst,
                                               W_edge, att_edge, cnt, recs);
        gat_scan   <<<NBIN * NCH, 1024, 0, stream>>>(recs, binstart, partial);
        gat_combine<<<(NN + 255) / 256, 256, 0, stream>>>(partial, bias, out, invd);
        gat_alpha  <<<NE / (256 * 4), 256, 0, stream>>>(src, dst, ea, asrc, adst,
                                                        W_edge, att_edge, invd, alpha);
    } else {
        float4* pack = (float4*)d_ws;
        float*  asrc = (float*)(pack + NN);
        float*  adst = asrc + NN;
        float*  invd = adst + NN;
        float*  partial = alpha;

        gat_node      <<<1024, 256, 0, stream>>>(x, W_src, att_src, att_dst, pack, asrc, adst, NN);
        gat_scan_fb   <<<FNSLICE * FNCHUNK, 1024, 0, stream>>>(src, dst, ea, pack, adst,
                                                               W_edge, att_edge, partial);
        gat_combine_fb<<<(NN + 255) / 256, 256, 0, stream>>>(partial, bias, out, invd);
        gat_alpha     <<<NE / (256 * 4), 256, 0, stream>>>(src, dst, ea, asrc, adst,
                                                           W_edge, att_edge, invd, alpha);
    }
}

// Round 9
// 223.079 us; speedup vs baseline: 1.4322x; 1.2491x over previous
//
#include <hip/hip_runtime.h>
#include <hip/hip_fp16.h>

#define NN 100000
#define NE 6400000
#define NEG_SLOPE 0.2f

// ---- binned path geometry ----
#define NBIN 32                // coarse dst-bins
#define BSLICE 3125            // nodes per bin (32*3125 = 100000 exactly)
#define NCH 16                 // scan chunks per bin -> 512 scan blocks
#define ABLK 512               // hist/scatter blocks
#define EPB (NE / ABLK)        // 12500 edges per block, %4 == 0
#define NODEBLK 1024           // node-pass blocks inside fused kernel

// ---- fallback (r5) geometry ----
#define FSLICE 10240
#define FNSLICE 10
#define FNCHUNK 20
#define FCHUNK (NE / FNCHUNK)

// ---------------- fused node pass + histogram ------------------------------
// blocks [0,1024): pack={h0,h1,a_src,a_dst} (one wave per node row)
// blocks [1024,1536): per-(block,bin) dst histogram
__global__ void gat_node_hist(const float* __restrict__ x, const float* __restrict__ W,
                              const float* __restrict__ att_src, const float* __restrict__ att_dst,
                              float4* __restrict__ pack, float* __restrict__ asrc,
                              float* __restrict__ adst,
                              const int* __restrict__ dst, int* __restrict__ cnt) {
    if (blockIdx.x < NODEBLK) {
        int gtid = blockIdx.x * 256 + threadIdx.x;
        int wave = gtid >> 6, lane = threadIdx.x & 63;
        const int nw = (NODEBLK * 256) >> 6;
        float as0 = att_src[0], as1 = att_src[1];
        float ad0 = att_dst[0], ad1 = att_dst[1];
        for (int node = wave; node < NN; node += nw) {
            float2 xx = *(const float2*)(x + (size_t)node * 128 + lane * 2);
            float2 w0 = *(const float2*)(W + lane * 4);
            float2 w1 = *(const float2*)(W + lane * 4 + 2);
            float c0 = xx.x * w0.x + xx.y * w1.x;
            float c1 = xx.x * w0.y + xx.y * w1.y;
            #pragma unroll
            for (int off = 32; off; off >>= 1) {
                c0 += __shfl_down(c0, off);
                c1 += __shfl_down(c1, off);
            }
            if (lane == 0) {
                float s = c0 * as0 + c1 * as1;
                float d = c0 * ad0 + c1 * ad1;
                pack[node] = make_float4(c0, c1, s, d);
                asrc[node] = s;
                adst[node] = d;
            }
        }
    } else {
        __shared__ unsigned h[NBIN];
        const int ablk = blockIdx.x - NODEBLK, t = threadIdx.x;
        if (t < NBIN) h[t] = 0;
        __syncthreads();
        const int b0 = ablk * EPB;
        for (int o = t * 4; o < EPB; o += 1024) {
            int4 d4 = *(const int4*)(dst + b0 + o);
            const int* dp = (const int*)&d4;
            #pragma unroll
            for (int u = 0; u < 4; ++u)
                atomicAdd(&h[(unsigned)dp[u] / BSLICE], 1u);
        }
        __syncthreads();
        if (t < NBIN) cnt[t * ABLK + ablk] = (int)h[t];
    }
}

// ---------------- prefix: per-(bin,block) bases ----------------------------
// 16 waves; wave w handles bins w and w+16; lane l covers 8 blocks.
__global__ __launch_bounds__(1024) void
gat_prefix(int* __restrict__ cnt, int* __restrict__ binstart) {
    __shared__ int btot[NBIN];
    __shared__ int bst[NBIN + 1];
    const int t = threadIdx.x, w = t >> 6, l = t & 63;
    int c[2][8], s[2], incl[2];
    #pragma unroll
    for (int q = 0; q < 2; ++q) {
        const int b = w + q * 16;
        int* row = cnt + b * ABLK;
        int ss = 0;
        #pragma unroll
        for (int j = 0; j < 8; ++j) { c[q][j] = row[l * 8 + j]; ss += c[q][j]; }
        int inc = ss;
        #pragma unroll
        for (int d = 1; d < 64; d <<= 1) {
            int v = __shfl_up(inc, d);
            if (l >= d) inc += v;
        }
        if (l == 63) btot[b] = inc;
        s[q] = ss; incl[q] = inc;
    }
    __syncthreads();
    if (t == 0) {
        int run = 0;
        for (int b = 0; b < NBIN; ++b) { bst[b] = run; run += btot[b]; }
        bst[NBIN] = run;
    }
    __syncthreads();
    #pragma unroll
    for (int q = 0; q < 2; ++q) {
        const int b = w + q * 16;
        int* row = cnt + b * ABLK;
        int base = bst[b] + incl[q] - s[q];
        #pragma unroll
        for (int j = 0; j < 8; ++j) { row[l * 8 + j] = base; base += c[q][j]; }
    }
    if (t <= NBIN) binstart[t] = bst[t];
}

// ---------------- scatter self-contained 8B records ------------------------
// rec = { f16(h0)|f16(h1)<<16 , f16(lrelu_logit)|off<<16 }
__global__ __launch_bounds__(1024) void
gat_scatter(const int* __restrict__ src, const int* __restrict__ dst,
            const float* __restrict__ ea, const float4* __restrict__ pack,
            const float* __restrict__ adst,
            const float* __restrict__ W_edge, const float* __restrict__ att_edge,
            const int* __restrict__ base, uint2* __restrict__ recs) {
    __shared__ unsigned cursor[NBIN];
    const int ablk = blockIdx.x, t = threadIdx.x;
    if (t < NBIN) cursor[t] = (unsigned)base[t * ABLK + ablk];
    __syncthreads();
    const float k = W_edge[0] * att_edge[0] + W_edge[1] * att_edge[1];
    const int b0 = ablk * EPB;
    for (int o = t * 4; o < EPB; o += 4096) {
        const int i = b0 + o;
        int4 s4 = *(const int4*)(src + i);
        int4 d4 = *(const int4*)(dst + i);
        float4 e4 = *(const float4*)(ea + i);
        const int* sp = (const int*)&s4;
        const int* dp = (const int*)&d4;
        const float* ep = (const float*)&e4;
        float4 ps[4];
        float  ad[4];
        #pragma unroll
        for (int u = 0; u < 4; ++u) {            // load-only stage
            ps[u] = pack[sp[u]];
            ad[u] = adst[dp[u]];
        }
        #pragma unroll
        for (int u = 0; u < 4; ++u) {
            unsigned d = (unsigned)dp[u];
            unsigned bin = d / BSLICE;
            unsigned off = d - bin * BSLICE;     // < 3125, fits 12 bits
            float al = ps[u].z + ad[u] + k * ep[u];
            al = al > 0.0f ? al : NEG_SLOPE * al;
            unsigned pos = atomicAdd(&cursor[bin], 1u);
            unsigned hh = (unsigned)__half_as_ushort(__float2half_rn(ps[u].x)) |
                          ((unsigned)__half_as_ushort(__float2half_rn(ps[u].y)) << 16);
            unsigned lo = (unsigned)__half_as_ushort(__float2half_rn(al)) | (off << 16);
            recs[pos] = make_uint2(hh, lo);
        }
    }
}

// ---------------- scan: 2 DS ops/record (f32 denom + pk_f16 num pair) ------
__global__ __launch_bounds__(1024) void
gat_scan(const uint2* __restrict__ recs, const int* __restrict__ binstart,
         float* __restrict__ partial) {
    __shared__ float   dacc[BSLICE];             // 12.5 KB
    __shared__ __half2 hacc[BSLICE];             // 12.5 KB  -> 2 blocks/CU
    const int blk = blockIdx.x, t = threadIdx.x;
    const int b = blk / NCH, c = blk % NCH;
    for (int j = t; j < BSLICE; j += 1024) {
        dacc[j] = 0.f;
        hacc[j] = __floats2half2_rn(0.f, 0.f);
    }
    __syncthreads();
    const int s0 = binstart[b], len = binstart[b + 1] - s0;
    const int c0 = s0 + (int)((long long)len * c / NCH);
    const int c1 = s0 + (int)((long long)len * (c + 1) / NCH);

#define PROC(r)                                                                \
    do {                                                                       \
        unsigned off_ = (r).y >> 16;                                           \
        float al_ = __half2float(__ushort_as_half((unsigned short)((r).y & 0xFFFFu))); \
        float ex_ = __expf(al_);                                               \
        float h0_ = __half2float(__ushort_as_half((unsigned short)((r).x & 0xFFFFu))); \
        float h1_ = __half2float(__ushort_as_half((unsigned short)((r).x >> 16)));     \
        atomicAdd(&dacc[off_], ex_);                                           \
        unsafeAtomicAdd(&hacc[off_], __floats2half2_rn(ex_ * h0_, ex_ * h1_)); \
    } while (0)

    int i = c0 + t;
    for (; i + 3072 < c1; i += 4096) {
        uint2 r0 = recs[i], r1 = recs[i + 1024], r2 = recs[i + 2048], r3 = recs[i + 3072];
        PROC(r0); PROC(r1); PROC(r2); PROC(r3);
    }
    for (; i < c1; i += 1024) {
        uint2 r = recs[i];
        PROC(r);
    }
#undef PROC
    __syncthreads();
    float* p = partial + (size_t)blk * (2 * BSLICE);
    unsigned* pu = (unsigned*)(p + BSLICE);
    const unsigned* hb = (const unsigned*)hacc;
    for (int j = t; j < BSLICE; j += 1024) {
        p[j] = dacc[j];
        pu[j] = hb[j];
    }
}

// ---------------- combine 16 partials: out, adiv={adst, 1/denom} -----------
__global__ void gat_combine(const float* __restrict__ partial,
                            const float* __restrict__ adst,
                            const float* __restrict__ bias,
                            float* __restrict__ out, float2* __restrict__ adiv) {
    int n = blockIdx.x * blockDim.x + threadIdx.x;
    if (n >= NN) return;
    int b = n / BSLICE, off = n % BSLICE;
    const float* pbase = partial + (size_t)(b * NCH) * (2 * BSLICE);
    float de = 0.f, n0 = 0.f, n1 = 0.f;
    for (int c = 0; c < NCH; ++c) {
        const float* p = pbase + (size_t)c * (2 * BSLICE);
        de += p[off];
        unsigned hb = ((const unsigned*)p)[BSLICE + off];
        float2 hf = __half22float2(*(const __half2*)&hb);
        n0 += hf.x; n1 += hf.y;
    }
    float inv = 1.0f / (de + 1e-16f);
    out[2 * n]     = n0 * inv + bias[0];
    out[2 * n + 1] = n1 * inv + bias[1];
    adiv[n] = make_float2(adst[n], inv);
}

// ---------------- alpha: recompute ex in f32, alpha = ex * inv[dst] --------
__global__ void gat_alpha(const int* __restrict__ src, const int* __restrict__ dst,
                          const float* __restrict__ ea,
                          const float* __restrict__ asrc, const float2* __restrict__ adiv,
                          const float* __restrict__ W_edge, const float* __restrict__ att_edge,
                          float* __restrict__ alpha) {
    const float k = W_edge[0] * att_edge[0] + W_edge[1] * att_edge[1];
    int i = (blockIdx.x * blockDim.x + threadIdx.x) * 4;
    if (i >= NE) return;
    int4   d4 = *(const int4*)(dst + i);
    int4   s4 = *(const int4*)(src + i);
    float4 e4 = *(const float4*)(ea + i);
    const int*   dp = (const int*)&d4;
    const int*   sp = (const int*)&s4;
    const float* ep = (const float*)&e4;
    float  as[4];
    float2 av[4];
    #pragma unroll
    for (int u = 0; u < 4; ++u) {                // load-only stage
        as[u] = asrc[sp[u]];
        av[u] = adiv[dp[u]];
    }
    float4 a;
    float* ap = (float*)&a;
    #pragma unroll
    for (int u = 0; u < 4; ++u) {
        float al = as[u] + av[u].x + k * ep[u];
        al = al > 0.0f ? al : NEG_SLOPE * al;
        ap[u] = __expf(al) * av[u].y;
    }
    *(float4*)(alpha + i) = a;
}

// ================== fallback (r5) kernels — used only if ws is small =======
__global__ void gat_node_fb(const float* __restrict__ x, const float* __restrict__ W,
                            const float* __restrict__ att_src, const float* __restrict__ att_dst,
                            float4* __restrict__ pack, float* __restrict__ asrc,
                            float* __restrict__ adst, int n) {
    int gtid = blockIdx.x * blockDim.x + threadIdx.x;
    int wave = gtid >> 6, lane = threadIdx.x & 63;
    int nw = (gridDim.x * blockDim.x) >> 6;
    float as0 = att_src[0], as1 = att_src[1];
    float ad0 = att_dst[0], ad1 = att_dst[1];
    for (int node = wave; node < n; node += nw) {
        float2 xx = *(const float2*)(x + (size_t)node * 128 + lane * 2);
        float2 w0 = *(const float2*)(W + lane * 4);
        float2 w1 = *(const float2*)(W + lane * 4 + 2);
        float c0 = xx.x * w0.x + xx.y * w1.x;
        float c1 = xx.x * w0.y + xx.y * w1.y;
        #pragma unroll
        for (int off = 32; off; off >>= 1) {
            c0 += __shfl_down(c0, off);
            c1 += __shfl_down(c1, off);
        }
        if (lane == 0) {
            float s = c0 * as0 + c1 * as1;
            float d = c0 * ad0 + c1 * ad1;
            pack[node] = make_float4(c0, c1, s, d);
            asrc[node] = s;
            adst[node] = d;
        }
    }
}

__global__ __launch_bounds__(1024) void
gat_scan_fb(const int* __restrict__ src, const int* __restrict__ dst,
            const float* __restrict__ ea, const float4* __restrict__ pack,
            const float* __restrict__ adst,
            const float* __restrict__ W_edge, const float* __restrict__ att_edge,
            float* __restrict__ partial) {
    __shared__ float sacc[FSLICE * 3];
    const int s = blockIdx.x / FNCHUNK;
    const int c = blockIdx.x % FNCHUNK;
    const int lo = s * FSLICE;
    for (int j = threadIdx.x; j < FSLICE * 3; j += 1024) sacc[j] = 0.0f;
    __syncthreads();
    const float k = W_edge[0] * att_edge[0] + W_edge[1] * att_edge[1];
    const int base = c * FCHUNK;
    for (int o = threadIdx.x * 8; o < FCHUNK; o += 1024 * 8) {
        const int i = base + o;
        int4   da = *(const int4*)(dst + i), db = *(const int4*)(dst + i + 4);
        int4   sa = *(const int4*)(src + i), sb = *(const int4*)(src + i + 4);
        float4 e0 = *(const float4*)(ea + i), e1 = *(const float4*)(ea + i + 4);
        int   dd[8] = {da.x, da.y, da.z, da.w, db.x, db.y, db.z, db.w};
        int   ss[8] = {sa.x, sa.y, sa.z, sa.w, sb.x, sb.y, sb.z, sb.w};
        float ee[8] = {e0.x, e0.y, e0.z, e0.w, e1.x, e1.y, e1.z, e1.w};
        unsigned off[8];
        float4 ps[8];
        float  ad[8];
        #pragma unroll
        for (int u = 0; u < 8; ++u) {
            off[u] = (unsigned)(dd[u] - lo);
            bool acc = off[u] < FSLICE;
            ps[u] = pack[acc ? ss[u] : 0];
            ad[u] = adst[acc ? dd[u] : lo];
        }
        #pragma unroll
        for (int u = 0; u < 8; ++u) {
            float al = ps[u].z + ad[u] + k * ee[u];
            al = al > 0.0f ? al : NEG_SLOPE * al;
            float ex = __expf(al);
            if (off[u] < FSLICE) {
                atomicAdd(&sacc[off[u] * 3],     ex);
                atomicAdd(&sacc[off[u] * 3 + 1], ex * ps[u].x);
                atomicAdd(&sacc[off[u] * 3 + 2], ex * ps[u].y);
            }
        }
    }
    __syncthreads();
    float* pout = partial + (size_t)blockIdx.x * (FSLICE * 3);
    for (int j = threadIdx.x; j < FSLICE * 3; j += 1024) pout[j] = sacc[j];
}

__global__ void gat_combine_fb(const float* __restrict__ partial,
                               const float* __restrict__ adst,
                               const float* __restrict__ bias,
                               float* __restrict__ out, float2* __restrict__ adiv) {
    int n = blockIdx.x * blockDim.x + threadIdx.x;
    if (n >= NN) return;
    int sl = n / FSLICE, off = n % FSLICE;
    const float* p = partial + (size_t)sl * FNCHUNK * (FSLICE * 3) + (size_t)off * 3;
    float de = 0.f, n0 = 0.f, n1 = 0.f;
    for (int c = 0; c < FNCHUNK; ++c, p += FSLICE * 3) {
        de += p[0]; n0 += p[1]; n1 += p[2];
    }
    float inv = 1.0f / (de + 1e-16f);
    out[2 * n]     = n0 * inv + bias[0];
    out[2 * n + 1] = n1 * inv + bias[1];
    adiv[n] = make_float2(adst[n], inv);
}

extern "C" void kernel_launch(void* const* d_in, const int* in_sizes, int n_in,
                              void* d_out, int out_size, void* d_ws, size_t ws_size,
                              hipStream_t stream) {
    const float* x        = (const float*)d_in[0];
    const int*   ei       = (const int*)  d_in[1];
    const float* ea       = (const float*)d_in[2];
    const float* W_src    = (const float*)d_in[3];
    const float* W_edge   = (const float*)d_in[4];
    const float* att_src  = (const float*)d_in[5];
    const float* att_dst  = (const float*)d_in[6];
    const float* att_edge = (const float*)d_in[7];
    const float* bias     = (const float*)d_in[8];

    float* out   = (float*)d_out;      // [N,2]
    float* alpha = out + 2 * NN;       // [E]: partial slabs first, then alpha

    const int* src = ei;
    const int* dst = ei + NE;

    // layout: recs | pack | asrc | adst | adiv | cnt | binstart
    size_t need = (size_t)NE * 8 + (size_t)NN * 16 + 2 * (size_t)NN * 4
                + (size_t)NN * 8 + (size_t)NBIN * ABLK * 4 + (NBIN + 1) * 4 + 64;

    if (ws_size >= need) {
        uint2*  recs = (uint2*)d_ws;
        float4* pack = (float4*)((char*)d_ws + (size_t)NE * 8);
        float*  asrc = (float*)(pack + NN);
        float*  adst = asrc + NN;
        float2* adiv = (float2*)(adst + NN);
        int*    cnt  = (int*)(adiv + NN);
        int*    binstart = cnt + NBIN * ABLK;
        float*  partial = alpha;   // 512 * 25000 B = 12.8 MB <= 25.6 MB

        gat_node_hist<<<NODEBLK + ABLK, 256, 0, stream>>>(x, W_src, att_src, att_dst,
                                                          pack, asrc, adst, dst, cnt);
        gat_prefix <<<1, 1024, 0, stream>>>(cnt, binstart);
        gat_scatter<<<ABLK, 1024, 0, stream>>>(src, dst, ea, pack, adst,
                                               W_edge, att_edge, cnt, recs);
        gat_scan   <<<NBIN * NCH, 1024, 0, stream>>>(recs, binstart, partial);
        gat_combine<<<(NN + 255) / 256, 256, 0, stream>>>(partial, adst, bias, out, adiv);
        gat_alpha  <<<NE / (256 * 4), 256, 0, stream>>>(src, dst, ea, asrc, adiv,
                                                        W_edge, att_edge, alpha);
    } else {
        float4* pack = (float4*)d_ws;
        float*  asrc = (float*)(pack + NN);
        float*  adst = asrc + NN;
        float2* adiv = (float2*)(adst + NN);
        float*  partial = alpha;

        gat_node_fb   <<<1024, 256, 0, stream>>>(x, W_src, att_src, att_dst, pack, asrc, adst, NN);
        gat_scan_fb   <<<FNSLICE * FNCHUNK, 1024, 0, stream>>>(src, dst, ea, pack, adst,
                                                               W_edge, att_edge, partial);
        gat_combine_fb<<<(NN + 255) / 256, 256, 0, stream>>>(partial, adst, bias, out, adiv);
        gat_alpha     <<<NE / (256 * 4), 256, 0, stream>>>(src, dst, ea, asrc, adiv,
                                                           W_edge, att_edge, alpha);
    }
}